// Round 10
// baseline (236.405 us; speedup 1.0000x reference)
//
#include <hip/hip_runtime.h>
#include <cmath>

#define D 128
#define NCLS 40
#define GG 391           // gemm grid for N=50000, 128 rows/block

typedef __bf16 bfrag __attribute__((ext_vector_type(8)));
typedef __bf16 bf2 __attribute__((ext_vector_type(2)));
typedef float ffrag __attribute__((ext_vector_type(4)));
typedef unsigned int u32;

// ---------------- K1: gemm1 (fp32 A, in-LDS W1 cvt)  ∥  deg_count ----------------
__global__ __launch_bounds__(256) void gemm1_deg(const float* __restrict__ A, const float* __restrict__ W1,
                                                 __bf16* __restrict__ C, int N,
                                                 const int* __restrict__ dst, int* __restrict__ count, int E) {
  __shared__ __align__(16) __bf16 Bs[128][136];
  if (blockIdx.x >= GG) {  // degree-count role
    int e = (blockIdx.x - GG) * 256 + threadIdx.x;
    if (e < E) atomicAdd(&count[dst[e]], 1);
    return;
  }
  const int tid = threadIdx.x;
  const int wave = tid >> 6, lane = tid & 63;
  const int row0 = blockIdx.x * 128 + wave * 32;
  const int koff = (lane >> 4) * 8;

  // stage W1 -> LDS transposed + converted (coalesced fp32 read)
  for (int i = tid; i < D * D; i += 256) {
    int k = i >> 7, n = i & 127;
    Bs[n][k] = (__bf16)W1[i];
  }

  bfrag a[2][4];
#pragma unroll
  for (int mt = 0; mt < 2; ++mt) {
    int r = row0 + mt * 16 + (lane & 15);
    int rc = r < N ? r : N - 1;
    const float* p = A + (size_t)rc * D;
#pragma unroll
    for (int kk = 0; kk < 4; ++kk) {
      float4 u = *(const float4*)(p + kk * 32 + koff);
      float4 v = *(const float4*)(p + kk * 32 + koff + 4);
      bfrag f;
      f[0] = (__bf16)u.x; f[1] = (__bf16)u.y; f[2] = (__bf16)u.z; f[3] = (__bf16)u.w;
      f[4] = (__bf16)v.x; f[5] = (__bf16)v.y; f[6] = (__bf16)v.z; f[7] = (__bf16)v.w;
      a[mt][kk] = f;
    }
  }
  __syncthreads();

  ffrag acc[2][8];
#pragma unroll
  for (int mt = 0; mt < 2; ++mt)
#pragma unroll
    for (int n = 0; n < 8; ++n) acc[mt][n] = (ffrag){0.f, 0.f, 0.f, 0.f};

#pragma unroll
  for (int kk = 0; kk < 4; ++kk) {
#pragma unroll
    for (int n = 0; n < 8; ++n) {
      bfrag b = *(const bfrag*)(&Bs[n * 16 + (lane & 15)][kk * 32 + koff]);
      acc[0][n] = __builtin_amdgcn_mfma_f32_16x16x32_bf16(a[0][kk], b, acc[0][n], 0, 0, 0);
      acc[1][n] = __builtin_amdgcn_mfma_f32_16x16x32_bf16(a[1][kk], b, acc[1][n], 0, 0, 0);
    }
  }

  int ocol = lane & 15;
#pragma unroll
  for (int mt = 0; mt < 2; ++mt) {
    int orow0 = row0 + mt * 16 + (lane >> 4) * 4;
#pragma unroll
    for (int n = 0; n < 8; ++n)
#pragma unroll
      for (int i = 0; i < 4; ++i) {
        int r = orow0 + i;
        if (r < N) C[(size_t)r * D + n * 16 + ocol] = (__bf16)acc[mt][n][i];
      }
  }
}

// ---------------- K2: per-block exclusive scan (dinv fused) ----------------
__device__ inline int wave_incl_scan(int x, int lane) {
#pragma unroll
  for (int off = 1; off < 64; off <<= 1) {
    int y = __shfl_up(x, off, 64);
    if (lane >= off) x += y;
  }
  return x;
}

__global__ __launch_bounds__(256) void scan_block(const int* __restrict__ deg, float* __restrict__ dinv,
                                                  int* __restrict__ local, int* __restrict__ bsum, int n) {
  int i = blockIdx.x * 256 + threadIdx.x;
  int lane = threadIdx.x & 63, wid = threadIdx.x >> 6;
  int v = (i < n) ? deg[i] : 0;
  if (i < n) dinv[i] = rsqrtf((float)v + 1.0f);  // +1 = self-loop
  int x = wave_incl_scan(v, lane);
  __shared__ int ws4[4];
  if (lane == 63) ws4[wid] = x;
  __syncthreads();
  int wb = 0;
#pragma unroll
  for (int j = 0; j < 4; ++j) wb += (j < wid) ? ws4[j] : 0;
  if (i < n) local[i] = wb + x - v;
  if (threadIdx.x == 255) bsum[blockIdx.x] = wb + x;
}

// ---------------- K3: add block prefix ----------------
__global__ __launch_bounds__(256) void scan_add2(int* __restrict__ rowptr, int* __restrict__ cursor,
                                                 const int* __restrict__ bsum, int n, int E, int nb) {
  const int tid = threadIdx.x;
  const int lane = tid & 63, wid = tid >> 6;
  int v = (tid < nb && tid < (int)blockIdx.x) ? bsum[tid] : 0;
#pragma unroll
  for (int off = 32; off > 0; off >>= 1) v += __shfl_down(v, off, 64);
  __shared__ int ws4[4];
  __shared__ int offs;
  if (lane == 0) ws4[wid] = v;
  __syncthreads();
  if (tid == 0) offs = ws4[0] + ws4[1] + ws4[2] + ws4[3];
  __syncthreads();
  int i = blockIdx.x * 256 + tid;
  if (i < n) {
    int r = rowptr[i] + offs;
    rowptr[i] = r;
    cursor[i] = r;
  }
  if (i == 0) rowptr[n] = E;
}

// ---------------- K4: CSR fill (src only, 4 B/edge) ----------------
__global__ __launch_bounds__(256) void fill_csr(const int* __restrict__ src, const int* __restrict__ dst,
                                                int* __restrict__ cursor, int* __restrict__ csr_s, int E) {
  int e = blockIdx.x * 256 + threadIdx.x;
  if (e < E) {
    int s = src[e], d = dst[e];
    int pos = atomicAdd(&cursor[d], 1);
    csr_s[pos] = s;
  }
}

// ---------------- gather: cooperative edge+dinv preload, unroll-8 rows ----------------
__global__ __launch_bounds__(256) void gather_bf16(const __bf16* __restrict__ t, const int* __restrict__ row_ptr,
                                                   const int* __restrict__ csr_s, const float* __restrict__ dinv,
                                                   const float* __restrict__ bias, __bf16* __restrict__ out, int N) {
  int node = blockIdx.x * 4 + (threadIdx.x >> 6);
  if (node >= N) return;
  int lane = threadIdx.x & 63;
  float dv = dinv[node];
  bf2 tv = *(const bf2*)(t + (size_t)node * D + lane * 2);
  float ax = dv * dv * (float)tv[0];
  float ay = dv * dv * (float)tv[1];
  int beg = __builtin_amdgcn_readfirstlane(row_ptr[node]);
  int end = __builtin_amdgcn_readfirstlane(row_ptr[node + 1]);
  int cnt = end - beg;
  int jmax = cnt <= 64 ? cnt : 64;
  // cooperative preload: src ids + their dinv, premultiplied by dv
  int es = 0; float ews = 0.0f;
  if (lane < jmax) {
    es = csr_s[beg + lane];
    ews = dinv[es] * dv;
  }
  int j = 0;
  for (; j + 8 <= jmax; j += 8) {
    int s0 = __shfl(es, j),     s1 = __shfl(es, j + 1), s2 = __shfl(es, j + 2), s3 = __shfl(es, j + 3);
    int s4 = __shfl(es, j + 4), s5 = __shfl(es, j + 5), s6 = __shfl(es, j + 6), s7 = __shfl(es, j + 7);
    float w0 = __shfl(ews, j),     w1 = __shfl(ews, j + 1), w2 = __shfl(ews, j + 2), w3 = __shfl(ews, j + 3);
    float w4 = __shfl(ews, j + 4), w5 = __shfl(ews, j + 5), w6 = __shfl(ews, j + 6), w7 = __shfl(ews, j + 7);
    bf2 r0 = *(const bf2*)(t + (size_t)s0 * D + lane * 2);
    bf2 r1 = *(const bf2*)(t + (size_t)s1 * D + lane * 2);
    bf2 r2 = *(const bf2*)(t + (size_t)s2 * D + lane * 2);
    bf2 r3 = *(const bf2*)(t + (size_t)s3 * D + lane * 2);
    bf2 r4 = *(const bf2*)(t + (size_t)s4 * D + lane * 2);
    bf2 r5 = *(const bf2*)(t + (size_t)s5 * D + lane * 2);
    bf2 r6 = *(const bf2*)(t + (size_t)s6 * D + lane * 2);
    bf2 r7 = *(const bf2*)(t + (size_t)s7 * D + lane * 2);
    ax += w0 * (float)r0[0]; ay += w0 * (float)r0[1];
    ax += w1 * (float)r1[0]; ay += w1 * (float)r1[1];
    ax += w2 * (float)r2[0]; ay += w2 * (float)r2[1];
    ax += w3 * (float)r3[0]; ay += w3 * (float)r3[1];
    ax += w4 * (float)r4[0]; ay += w4 * (float)r4[1];
    ax += w5 * (float)r5[0]; ay += w5 * (float)r5[1];
    ax += w6 * (float)r6[0]; ay += w6 * (float)r6[1];
    ax += w7 * (float)r7[0]; ay += w7 * (float)r7[1];
  }
  for (; j + 4 <= jmax; j += 4) {
    int s0 = __shfl(es, j), s1 = __shfl(es, j + 1), s2 = __shfl(es, j + 2), s3 = __shfl(es, j + 3);
    float w0 = __shfl(ews, j), w1 = __shfl(ews, j + 1), w2 = __shfl(ews, j + 2), w3 = __shfl(ews, j + 3);
    bf2 r0 = *(const bf2*)(t + (size_t)s0 * D + lane * 2);
    bf2 r1 = *(const bf2*)(t + (size_t)s1 * D + lane * 2);
    bf2 r2 = *(const bf2*)(t + (size_t)s2 * D + lane * 2);
    bf2 r3 = *(const bf2*)(t + (size_t)s3 * D + lane * 2);
    ax += w0 * (float)r0[0]; ay += w0 * (float)r0[1];
    ax += w1 * (float)r1[0]; ay += w1 * (float)r1[1];
    ax += w2 * (float)r2[0]; ay += w2 * (float)r2[1];
    ax += w3 * (float)r3[0]; ay += w3 * (float)r3[1];
  }
  for (; j < jmax; ++j) {
    int s = __shfl(es, j);
    float w = __shfl(ews, j);
    bf2 r = *(const bf2*)(t + (size_t)s * D + lane * 2);
    ax += w * (float)r[0]; ay += w * (float)r[1];
  }
  for (; j < cnt; ++j) {  // degree > 64: effectively never
    int s = csr_s[beg + j];
    float w = dinv[s] * dv;
    bf2 r = *(const bf2*)(t + (size_t)s * D + lane * 2);
    ax += w * (float)r[0]; ay += w * (float)r[1];
  }
  float2 bv = *(const float2*)(bias + lane * 2);
  bf2 o;
  o[0] = (__bf16)tanhf(ax + bv.x);
  o[1] = (__bf16)tanhf(ay + bv.y);
  *(u32*)(out + (size_t)node * D + lane * 2) = *(u32*)&o;
}

// ---------------- MFMA GEMM (bf16 A, in-LDS W2 cvt) for layer 2 ----------------
__global__ __launch_bounds__(256) void gemm_mfma(const __bf16* __restrict__ A, const float* __restrict__ W2,
                                                 __bf16* __restrict__ C, int N) {
  __shared__ __align__(16) __bf16 Bs[128][136];
  const int tid = threadIdx.x;
  const int wave = tid >> 6, lane = tid & 63;
  const int row0 = blockIdx.x * 128 + wave * 32;
  const int koff = (lane >> 4) * 8;

  for (int i = tid; i < D * D; i += 256) {
    int k = i >> 7, n = i & 127;
    Bs[n][k] = (__bf16)W2[i];
  }

  bfrag a[2][4];
#pragma unroll
  for (int mt = 0; mt < 2; ++mt) {
    int r = row0 + mt * 16 + (lane & 15);
    int rc = r < N ? r : N - 1;
#pragma unroll
    for (int kk = 0; kk < 4; ++kk)
      a[mt][kk] = *(const bfrag*)(A + (size_t)rc * D + kk * 32 + koff);
  }
  __syncthreads();

  ffrag acc[2][8];
#pragma unroll
  for (int mt = 0; mt < 2; ++mt)
#pragma unroll
    for (int n = 0; n < 8; ++n) acc[mt][n] = (ffrag){0.f, 0.f, 0.f, 0.f};

#pragma unroll
  for (int kk = 0; kk < 4; ++kk) {
#pragma unroll
    for (int n = 0; n < 8; ++n) {
      bfrag b = *(const bfrag*)(&Bs[n * 16 + (lane & 15)][kk * 32 + koff]);
      acc[0][n] = __builtin_amdgcn_mfma_f32_16x16x32_bf16(a[0][kk], b, acc[0][n], 0, 0, 0);
      acc[1][n] = __builtin_amdgcn_mfma_f32_16x16x32_bf16(a[1][kk], b, acc[1][n], 0, 0, 0);
    }
  }

  int ocol = lane & 15;
#pragma unroll
  for (int mt = 0; mt < 2; ++mt) {
    int orow0 = row0 + mt * 16 + (lane >> 4) * 4;
#pragma unroll
    for (int n = 0; n < 8; ++n)
#pragma unroll
      for (int i = 0; i < 4; ++i) {
        int r = orow0 + i;
        if (r < N) C[(size_t)r * D + n * 16 + ocol] = (__bf16)acc[mt][n][i];
      }
  }
}

// ---------------- MFMA head (in-LDS Wlin cvt) ----------------
__global__ __launch_bounds__(256) void head_mfma(const __bf16* __restrict__ H, const float* __restrict__ Wl,
                                                 const float* __restrict__ bias, float* __restrict__ out, int N) {
  __shared__ __align__(16) __bf16 Ws[48][136];
  const int tid = threadIdx.x;
  const int wave = tid >> 6, lane = tid & 63;
  const int row0 = blockIdx.x * 128 + wave * 32;
  const int koff = (lane >> 4) * 8;

  // j < 5120: coalesced Wl read -> Ws[n][k]; j >= 5120: zero-fill rows 40..47 (k<128)
  for (int j = tid; j < 5120 + 8 * 128; j += 256) {
    if (j < 5120) {
      int k = j / NCLS, n = j - k * NCLS;
      Ws[n][k] = (__bf16)Wl[j];
    } else {
      int idx = j - 5120;
      Ws[40 + (idx >> 7)][idx & 127] = (__bf16)0.0f;
    }
  }

  bfrag a[2][4];
#pragma unroll
  for (int mt = 0; mt < 2; ++mt) {
    int r = row0 + mt * 16 + (lane & 15);
    int rc = r < N ? r : N - 1;
#pragma unroll
    for (int kk = 0; kk < 4; ++kk)
      a[mt][kk] = *(const bfrag*)(H + (size_t)rc * D + kk * 32 + koff);
  }
  __syncthreads();

  ffrag acc[2][3];
#pragma unroll
  for (int mt = 0; mt < 2; ++mt)
#pragma unroll
    for (int n = 0; n < 3; ++n) acc[mt][n] = (ffrag){0.f, 0.f, 0.f, 0.f};

#pragma unroll
  for (int kk = 0; kk < 4; ++kk) {
#pragma unroll
    for (int n = 0; n < 3; ++n) {
      bfrag b = *(const bfrag*)(&Ws[n * 16 + (lane & 15)][kk * 32 + koff]);
      acc[0][n] = __builtin_amdgcn_mfma_f32_16x16x32_bf16(a[0][kk], b, acc[0][n], 0, 0, 0);
      acc[1][n] = __builtin_amdgcn_mfma_f32_16x16x32_bf16(a[1][kk], b, acc[1][n], 0, 0, 0);
    }
  }

  int ocol = lane & 15;
#pragma unroll
  for (int mt = 0; mt < 2; ++mt) {
    int orow0 = row0 + mt * 16 + (lane >> 4) * 4;
#pragma unroll
    for (int n = 0; n < 3; ++n) {
      int c = n * 16 + ocol;
      if (c < NCLS) {
#pragma unroll
        for (int i = 0; i < 4; ++i) {
          int r = orow0 + i;
          if (r < N) out[(size_t)r * NCLS + c] = acc[mt][n][i] + bias[c];
        }
      }
    }
  }
}

extern "C" void kernel_launch(void* const* d_in, const int* in_sizes, int n_in,
                              void* d_out, int out_size, void* d_ws, size_t ws_size,
                              hipStream_t stream) {
  const float* x    = (const float*)d_in[0];
  const int*   ei   = (const int*)d_in[1];
  const float* W1   = (const float*)d_in[2];
  const float* b1   = (const float*)d_in[3];
  const float* W2   = (const float*)d_in[4];
  const float* b2   = (const float*)d_in[5];
  const float* Wlin = (const float*)d_in[6];
  const float* blin = (const float*)d_in[7];
  float* out = (float*)d_out;

  const int N = in_sizes[0] / D;   // 50000
  const int E = in_sizes[1] / 2;   // 600000
  const int* srcp = ei;
  const int* dstp = ei + E;

  // workspace layout (~30 MB)
  char* ws = (char*)d_ws;
  float*  dinv   = (float*)(ws);                     // 200 KB
  int*    rowptr = (int*)(ws + (size_t)262144);      // N+1 ints
  int*    cursor = (int*)(ws + (size_t)524288);      // doubles as deg/count
  int*    bsum   = (int*)(ws + (size_t)786432);      // 196 ints
  int*    csr_s  = (int*)(ws + (size_t)1048576);     // 2.4 MB
  __bf16* tb     = (__bf16*)(ws + (size_t)4194304);  // 12.8 MB
  __bf16* hb     = (__bf16*)(ws + (size_t)20971520); // 12.8 MB

  const int nb = (N + 255) / 256;     // 196
  const int eb = (E + 255) / 256;     // 2344
  dim3 b256(256);

  // zero count
  hipMemsetAsync(cursor, 0, (size_t)N * sizeof(int), stream);
  // K1: gemm1 (in-LDS W1 cvt) ∥ deg_count
  gemm1_deg<<<GG + eb, b256, 0, stream>>>(x, W1, tb, N, dstp, cursor, E);
  // K2-K4: scan + fill
  scan_block<<<nb, b256, 0, stream>>>(cursor, dinv, rowptr, bsum, N);
  scan_add2<<<nb, b256, 0, stream>>>(rowptr, cursor, bsum, N, E, nb);
  fill_csr<<<eb, b256, 0, stream>>>(srcp, dstp, cursor, csr_s, E);
  // layer 1 propagate
  gather_bf16<<<(N + 3) / 4, b256, 0, stream>>>(tb, rowptr, csr_s, dinv, b1, hb, N);
  // layer 2
  gemm_mfma<<<GG, b256, 0, stream>>>(hb, W2, tb, N);
  gather_bf16<<<(N + 3) / 4, b256, 0, stream>>>(tb, rowptr, csr_s, dinv, b2, hb, N);
  // head
  head_mfma<<<GG, b256, 0, stream>>>(hb, Wlin, blin, out, N);
}

// Round 11
// 225.227 us; speedup vs baseline: 1.0496x; 1.0496x over previous
//
#include <hip/hip_runtime.h>
#include <cmath>

#define D 128
#define NCLS 40
#define GG 391           // gemm grid for N=50000, 128 rows/block
#define CVT_BLOCKS 152   // 38912 weight elems / 256

typedef __bf16 bfrag __attribute__((ext_vector_type(8)));
typedef __bf16 bf2 __attribute__((ext_vector_type(2)));
typedef float ffrag __attribute__((ext_vector_type(4)));
typedef unsigned int u32;

struct __align__(8) Edge { int s; float w; };

// ---------------- K1: weights -> bf16 transposed  ∥  zero(count) ----------------
__global__ __launch_bounds__(256) void init_kernel(const float* __restrict__ W1, const float* __restrict__ W2,
                                                   const float* __restrict__ Wl, __bf16* __restrict__ Wt1,
                                                   __bf16* __restrict__ Wt2, __bf16* __restrict__ Wlt,
                                                   int* __restrict__ count, int N) {
  int b = blockIdx.x;
  if (b < CVT_BLOCKS) {
    int i = b * 256 + threadIdx.x;
    if (i < 16384) {
      int n = i >> 7, k = i & 127;
      Wt1[i] = (__bf16)W1[k * D + n];
    } else if (i < 32768) {
      int j = i - 16384;
      int n = j >> 7, k = j & 127;
      Wt2[j] = (__bf16)W2[k * D + n];
    } else if (i < 32768 + 48 * D) {
      int j = i - 32768;
      int n = j >> 7, k = j & 127;
      Wlt[j] = (n < NCLS) ? (__bf16)Wl[k * NCLS + n] : (__bf16)0.0f;
    }
  } else {
    int i = (b - CVT_BLOCKS) * 256 + threadIdx.x;
    if (i < N) count[i] = 0;
  }
}

// ---------------- K2: gemm1 (fp32 A -> bf16 C)  ∥  deg_count ----------------
__global__ __launch_bounds__(256) void gemm1_deg(const float* __restrict__ A, const __bf16* __restrict__ Wt,
                                                 __bf16* __restrict__ C, int N,
                                                 const int* __restrict__ dst, int* __restrict__ count, int E) {
  __shared__ __align__(16) __bf16 Bs[128][136];
  if (blockIdx.x >= GG) {  // degree-count role
    int e = (blockIdx.x - GG) * 256 + threadIdx.x;
    if (e < E) atomicAdd(&count[dst[e]], 1);
    return;
  }
  const int tid = threadIdx.x;
  const int wave = tid >> 6, lane = tid & 63;
  const int row0 = blockIdx.x * 128 + wave * 32;
  const int koff = (lane >> 4) * 8;

  for (int i = tid; i < 128 * 16; i += 256) {
    int n = i >> 4, seg = i & 15;
    *(uint4*)&Bs[n][seg * 8] = *(const uint4*)(Wt + n * D + seg * 8);
  }

  bfrag a[2][4];
#pragma unroll
  for (int mt = 0; mt < 2; ++mt) {
    int r = row0 + mt * 16 + (lane & 15);
    int rc = r < N ? r : N - 1;
    const float* p = A + (size_t)rc * D;
#pragma unroll
    for (int kk = 0; kk < 4; ++kk) {
      float4 u = *(const float4*)(p + kk * 32 + koff);
      float4 v = *(const float4*)(p + kk * 32 + koff + 4);
      bfrag f;
      f[0] = (__bf16)u.x; f[1] = (__bf16)u.y; f[2] = (__bf16)u.z; f[3] = (__bf16)u.w;
      f[4] = (__bf16)v.x; f[5] = (__bf16)v.y; f[6] = (__bf16)v.z; f[7] = (__bf16)v.w;
      a[mt][kk] = f;
    }
  }
  __syncthreads();

  ffrag acc[2][8];
#pragma unroll
  for (int mt = 0; mt < 2; ++mt)
#pragma unroll
    for (int n = 0; n < 8; ++n) acc[mt][n] = (ffrag){0.f, 0.f, 0.f, 0.f};

#pragma unroll
  for (int kk = 0; kk < 4; ++kk) {
#pragma unroll
    for (int n = 0; n < 8; ++n) {
      bfrag b = *(const bfrag*)(&Bs[n * 16 + (lane & 15)][kk * 32 + koff]);
      acc[0][n] = __builtin_amdgcn_mfma_f32_16x16x32_bf16(a[0][kk], b, acc[0][n], 0, 0, 0);
      acc[1][n] = __builtin_amdgcn_mfma_f32_16x16x32_bf16(a[1][kk], b, acc[1][n], 0, 0, 0);
    }
  }

  int ocol = lane & 15;
#pragma unroll
  for (int mt = 0; mt < 2; ++mt) {
    int orow0 = row0 + mt * 16 + (lane >> 4) * 4;
#pragma unroll
    for (int n = 0; n < 8; ++n)
#pragma unroll
      for (int i = 0; i < 4; ++i) {
        int r = orow0 + i;
        if (r < N) C[(size_t)r * D + n * 16 + ocol] = (__bf16)acc[mt][n][i];
      }
  }
}

// ---------------- K3: per-block exclusive scan (dinv fused) ----------------
__device__ inline int wave_incl_scan(int x, int lane) {
#pragma unroll
  for (int off = 1; off < 64; off <<= 1) {
    int y = __shfl_up(x, off, 64);
    if (lane >= off) x += y;
  }
  return x;
}

__global__ __launch_bounds__(256) void scan_block(const int* __restrict__ deg, float* __restrict__ dinv,
                                                  int* __restrict__ local, int* __restrict__ bsum, int n) {
  int i = blockIdx.x * 256 + threadIdx.x;
  int lane = threadIdx.x & 63, wid = threadIdx.x >> 6;
  int v = (i < n) ? deg[i] : 0;
  if (i < n) dinv[i] = rsqrtf((float)v + 1.0f);  // +1 = self-loop
  int x = wave_incl_scan(v, lane);
  __shared__ int ws4[4];
  if (lane == 63) ws4[wid] = x;
  __syncthreads();
  int wb = 0;
#pragma unroll
  for (int j = 0; j < 4; ++j) wb += (j < wid) ? ws4[j] : 0;
  if (i < n) local[i] = wb + x - v;
  if (threadIdx.x == 255) bsum[blockIdx.x] = wb + x;
}

// ---------------- K4: add block prefix (self-computed from bsum) ----------------
__global__ __launch_bounds__(256) void scan_add2(int* __restrict__ rowptr, int* __restrict__ cursor,
                                                 const int* __restrict__ bsum, int n, int E, int nb) {
  const int tid = threadIdx.x;
  const int lane = tid & 63, wid = tid >> 6;
  // reduce bsum[0 .. blockIdx.x) across the block (nb <= 256)
  int v = (tid < nb && tid < (int)blockIdx.x) ? bsum[tid] : 0;
#pragma unroll
  for (int off = 32; off > 0; off >>= 1) v += __shfl_down(v, off, 64);
  __shared__ int ws4[4];
  __shared__ int offs;
  if (lane == 0) ws4[wid] = v;
  __syncthreads();
  if (tid == 0) offs = ws4[0] + ws4[1] + ws4[2] + ws4[3];
  __syncthreads();
  int i = blockIdx.x * 256 + tid;
  if (i < n) {
    int r = rowptr[i] + offs;
    rowptr[i] = r;
    cursor[i] = r;
  }
  if (i == 0) rowptr[n] = E;
}

// ---------------- K5: CSR fill ----------------
__global__ __launch_bounds__(256) void fill_csr(const int* __restrict__ src, const int* __restrict__ dst,
                                                const float* __restrict__ dinv, int* __restrict__ cursor,
                                                Edge* __restrict__ csr, int E) {
  int e = blockIdx.x * 256 + threadIdx.x;
  if (e < E) {
    int s = src[e], d = dst[e];
    int pos = atomicAdd(&cursor[d], 1);
    Edge ed; ed.s = s; ed.w = dinv[s] * dinv[d];
    csr[pos] = ed;
  }
}

// ---------------- gather: cooperative edge preload + row-load pipeline ----------------
__global__ __launch_bounds__(256) void gather_bf16(const __bf16* __restrict__ t, const int* __restrict__ row_ptr,
                                                   const Edge* __restrict__ csr, const float* __restrict__ dinv,
                                                   const float* __restrict__ bias, __bf16* __restrict__ out, int N) {
  int node = blockIdx.x * 4 + (threadIdx.x >> 6);
  if (node >= N) return;
  int lane = threadIdx.x & 63;
  float dv = dinv[node];
  bf2 tv = *(const bf2*)(t + (size_t)node * D + lane * 2);
  float ax = dv * dv * (float)tv[0];
  float ay = dv * dv * (float)tv[1];
  int beg = __builtin_amdgcn_readfirstlane(row_ptr[node]);
  int end = __builtin_amdgcn_readfirstlane(row_ptr[node + 1]);
  int cnt = end - beg;
  int jmax = cnt <= 64 ? cnt : 64;
  int es = 0; float ew = 0.0f;
  if (lane < jmax) {
    Edge ed = csr[beg + lane];
    es = ed.s; ew = ed.w;
  }
  int j = 0;
  for (; j + 4 <= jmax; j += 4) {
    int s0 = __shfl(es, j), s1 = __shfl(es, j + 1), s2 = __shfl(es, j + 2), s3 = __shfl(es, j + 3);
    float w0 = __shfl(ew, j), w1 = __shfl(ew, j + 1), w2 = __shfl(ew, j + 2), w3 = __shfl(ew, j + 3);
    bf2 r0 = *(const bf2*)(t + (size_t)s0 * D + lane * 2);
    bf2 r1 = *(const bf2*)(t + (size_t)s1 * D + lane * 2);
    bf2 r2 = *(const bf2*)(t + (size_t)s2 * D + lane * 2);
    bf2 r3 = *(const bf2*)(t + (size_t)s3 * D + lane * 2);
    ax += w0 * (float)r0[0]; ay += w0 * (float)r0[1];
    ax += w1 * (float)r1[0]; ay += w1 * (float)r1[1];
    ax += w2 * (float)r2[0]; ay += w2 * (float)r2[1];
    ax += w3 * (float)r3[0]; ay += w3 * (float)r3[1];
  }
  for (; j < jmax; ++j) {
    int s = __shfl(es, j);
    float w = __shfl(ew, j);
    bf2 r = *(const bf2*)(t + (size_t)s * D + lane * 2);
    ax += w * (float)r[0]; ay += w * (float)r[1];
  }
  for (; j < cnt; ++j) {  // degree > 64: effectively never
    Edge ed = csr[beg + j];
    bf2 r = *(const bf2*)(t + (size_t)ed.s * D + lane * 2);
    ax += ed.w * (float)r[0]; ay += ed.w * (float)r[1];
  }
  float2 bv = *(const float2*)(bias + lane * 2);
  bf2 o;
  o[0] = (__bf16)tanhf(ax + bv.x);
  o[1] = (__bf16)tanhf(ay + bv.y);
  __builtin_nontemporal_store(*(u32*)&o, (u32*)(out + (size_t)node * D + lane * 2));
}

// ---------------- MFMA GEMM (bf16 A) for layer 2 ----------------
__global__ __launch_bounds__(256) void gemm_mfma(const __bf16* __restrict__ A, const __bf16* __restrict__ Wt,
                                                 __bf16* __restrict__ C, int N) {
  __shared__ __align__(16) __bf16 Bs[128][136];
  const int tid = threadIdx.x;
  const int wave = tid >> 6, lane = tid & 63;
  const int row0 = blockIdx.x * 128 + wave * 32;
  const int koff = (lane >> 4) * 8;

  for (int i = tid; i < 128 * 16; i += 256) {
    int n = i >> 4, seg = i & 15;
    *(uint4*)&Bs[n][seg * 8] = *(const uint4*)(Wt + n * D + seg * 8);
  }

  bfrag a[2][4];
#pragma unroll
  for (int mt = 0; mt < 2; ++mt) {
    int r = row0 + mt * 16 + (lane & 15);
    int rc = r < N ? r : N - 1;
#pragma unroll
    for (int kk = 0; kk < 4; ++kk)
      a[mt][kk] = *(const bfrag*)(A + (size_t)rc * D + kk * 32 + koff);
  }
  __syncthreads();

  ffrag acc[2][8];
#pragma unroll
  for (int mt = 0; mt < 2; ++mt)
#pragma unroll
    for (int n = 0; n < 8; ++n) acc[mt][n] = (ffrag){0.f, 0.f, 0.f, 0.f};

#pragma unroll
  for (int kk = 0; kk < 4; ++kk) {
#pragma unroll
    for (int n = 0; n < 8; ++n) {
      bfrag b = *(const bfrag*)(&Bs[n * 16 + (lane & 15)][kk * 32 + koff]);
      acc[0][n] = __builtin_amdgcn_mfma_f32_16x16x32_bf16(a[0][kk], b, acc[0][n], 0, 0, 0);
      acc[1][n] = __builtin_amdgcn_mfma_f32_16x16x32_bf16(a[1][kk], b, acc[1][n], 0, 0, 0);
    }
  }

  int ocol = lane & 15;
#pragma unroll
  for (int mt = 0; mt < 2; ++mt) {
    int orow0 = row0 + mt * 16 + (lane >> 4) * 4;
#pragma unroll
    for (int n = 0; n < 8; ++n)
#pragma unroll
      for (int i = 0; i < 4; ++i) {
        int r = orow0 + i;
        if (r < N) C[(size_t)r * D + n * 16 + ocol] = (__bf16)acc[mt][n][i];
      }
  }
}

// ---------------- MFMA head ----------------
__global__ __launch_bounds__(256) void head_mfma(const __bf16* __restrict__ H, const __bf16* __restrict__ Wlt,
                                                 const float* __restrict__ bias, float* __restrict__ out, int N) {
  __shared__ __align__(16) __bf16 Ws[48][136];
  const int tid = threadIdx.x;
  const int wave = tid >> 6, lane = tid & 63;
  const int row0 = blockIdx.x * 128 + wave * 32;
  const int koff = (lane >> 4) * 8;

  for (int i = tid; i < 48 * 16; i += 256) {
    int n = i >> 4, seg = i & 15;
    *(uint4*)&Ws[n][seg * 8] = *(const uint4*)(Wlt + n * D + seg * 8);
  }

  bfrag a[2][4];
#pragma unroll
  for (int mt = 0; mt < 2; ++mt) {
    int r = row0 + mt * 16 + (lane & 15);
    int rc = r < N ? r : N - 1;
#pragma unroll
    for (int kk = 0; kk < 4; ++kk)
      a[mt][kk] = *(const bfrag*)(H + (size_t)rc * D + kk * 32 + koff);
  }
  __syncthreads();

  ffrag acc[2][3];
#pragma unroll
  for (int mt = 0; mt < 2; ++mt)
#pragma unroll
    for (int n = 0; n < 3; ++n) acc[mt][n] = (ffrag){0.f, 0.f, 0.f, 0.f};

#pragma unroll
  for (int kk = 0; kk < 4; ++kk) {
#pragma unroll
    for (int n = 0; n < 3; ++n) {
      bfrag b = *(const bfrag*)(&Ws[n * 16 + (lane & 15)][kk * 32 + koff]);
      acc[0][n] = __builtin_amdgcn_mfma_f32_16x16x32_bf16(a[0][kk], b, acc[0][n], 0, 0, 0);
      acc[1][n] = __builtin_amdgcn_mfma_f32_16x16x32_bf16(a[1][kk], b, acc[1][n], 0, 0, 0);
    }
  }

  int ocol = lane & 15;
#pragma unroll
  for (int mt = 0; mt < 2; ++mt) {
    int orow0 = row0 + mt * 16 + (lane >> 4) * 4;
#pragma unroll
    for (int n = 0; n < 3; ++n) {
      int c = n * 16 + ocol;
      if (c < NCLS) {
#pragma unroll
        for (int i = 0; i < 4; ++i) {
          int r = orow0 + i;
          if (r < N) out[(size_t)r * NCLS + c] = acc[mt][n][i] + bias[c];
        }
      }
    }
  }
}

extern "C" void kernel_launch(void* const* d_in, const int* in_sizes, int n_in,
                              void* d_out, int out_size, void* d_ws, size_t ws_size,
                              hipStream_t stream) {
  const float* x    = (const float*)d_in[0];
  const int*   ei   = (const int*)d_in[1];
  const float* W1   = (const float*)d_in[2];
  const float* b1   = (const float*)d_in[3];
  const float* W2   = (const float*)d_in[4];
  const float* b2   = (const float*)d_in[5];
  const float* Wlin = (const float*)d_in[6];
  const float* blin = (const float*)d_in[7];
  float* out = (float*)d_out;

  const int N = in_sizes[0] / D;   // 50000
  const int E = in_sizes[1] / 2;   // 600000
  const int* srcp = ei;
  const int* dstp = ei + E;

  // workspace layout (~38 MB)
  char* ws = (char*)d_ws;
  float*  dinv   = (float*)(ws);                     // 200 KB
  int*    rowptr = (int*)(ws + (size_t)262144);      // N+1 ints
  int*    cursor = (int*)(ws + (size_t)524288);      // doubles as deg/count
  int*    bsum   = (int*)(ws + (size_t)786432);      // 196 ints
  __bf16* Wt1    = (__bf16*)(ws + (size_t)790528);   // 32 KB
  __bf16* Wt2    = (__bf16*)(ws + (size_t)823296);   // 32 KB
  __bf16* Wlt    = (__bf16*)(ws + (size_t)856064);   // 12.3 KB
  Edge*   csr    = (Edge*)(ws + (size_t)1048576);    // 4.8 MB
  __bf16* tb     = (__bf16*)(ws + (size_t)8388608);  // 12.8 MB
  __bf16* hb     = (__bf16*)(ws + (size_t)25165824); // 12.8 MB

  const int nb = (N + 255) / 256;     // 196
  const int eb = (E + 255) / 256;     // 2344
  dim3 b256(256);

  // K1: weights + count init
  init_kernel<<<CVT_BLOCKS + nb, b256, 0, stream>>>(W1, W2, Wlin, Wt1, Wt2, Wlt, cursor, N);
  // K2: gemm1 (needs Wt1) ∥ deg_count (needs zeroed count)
  gemm1_deg<<<GG + eb, b256, 0, stream>>>(x, Wt1, tb, N, dstp, cursor, E);
  // K3-K5: scan + fill
  scan_block<<<nb, b256, 0, stream>>>(cursor, dinv, rowptr, bsum, N);
  scan_add2<<<nb, b256, 0, stream>>>(rowptr, cursor, bsum, N, E, nb);
  fill_csr<<<eb, b256, 0, stream>>>(srcp, dstp, dinv, cursor, csr, E);
  // layer 1 propagate
  gather_bf16<<<(N + 3) / 4, b256, 0, stream>>>(tb, rowptr, csr, dinv, b1, hb, N);
  // layer 2
  gemm_mfma<<<GG, b256, 0, stream>>>(hb, Wt2, tb, N);
  gather_bf16<<<(N + 3) / 4, b256, 0, stream>>>(tb, rowptr, csr, dinv, b2, hb, N);
  // head
  head_mfma<<<GG, b256, 0, stream>>>(hb, Wlt, blin, out, N);
}